// Round 3
// baseline (403.239 us; speedup 1.0000x reference)
//
#include <hip/hip_runtime.h>
#include <hip/hip_bf16.h>
#include <stdint.h>

#define M_DIM 8192
#define N_DIM 4096
#define K_DIM 4096
#define RANK  16

#define BM 256
#define BN 256
#define BK 64
#define NKT (K_DIM / BK)   // 64 K-tiles

typedef __attribute__((ext_vector_type(8)))  __bf16 bf16x8;
typedef __attribute__((ext_vector_type(16))) float  f32x16;
typedef __attribute__((ext_vector_type(8)))  unsigned short u16x8;

__device__ __forceinline__ unsigned short f2bf(float f) {
    union { float f; uint32_t u; } c; c.f = f;
    uint32_t b = c.u;
    b += 0x7FFFu + ((b >> 16) & 1u);   // RNE (finite data)
    return (unsigned short)(b >> 16);
}

// ---------------- fused prep: W_eff build (blocks 0..4095) + x convert ----------------
#define CONV_BLOCKS 2048
__global__ __launch_bounds__(256) void prep_kernel(
    const float* __restrict__ x,
    const float* __restrict__ wp,   // [4096][1024]
    const float* __restrict__ lA,   // [16][4096]
    const float* __restrict__ lB,   // [4096][16]
    const int*   __restrict__ scaling,
    unsigned short* __restrict__ xb,     // [8192][4096] bf16
    unsigned short* __restrict__ weff) { // [4096][4096] bf16
    const int tid = threadIdx.x;
    if (blockIdx.x < N_DIM) {
        // ---- W_eff row ----
        int o = blockIdx.x;
        float s = (float)scaling[0];
        float b[RANK];
#pragma unroll
        for (int r = 0; r < RANK; ++r) b[r] = lB[o * RANK + r] * s;
#pragma unroll
        for (int ii = 0; ii < 16; ++ii) {
            int i = tid + ii * 256;
            float acc = wp[o * 1024 + (i & 1023)];
#pragma unroll
            for (int r = 0; r < RANK; ++r) acc = fmaf(b[r], lA[r * 4096 + i], acc);
            weff[(size_t)o * 4096 + i] = f2bf(acc);
        }
    } else {
        // ---- x fp32 -> bf16, 8 floats per thread-iter ----
        const int n8 = (M_DIM * K_DIM) / 8;
        int idx = (blockIdx.x - N_DIM) * 256 + tid;
        const int stride = CONV_BLOCKS * 256;
        for (int i = idx; i < n8; i += stride) {
            float4 v0 = reinterpret_cast<const float4*>(x)[2 * i];
            float4 v1 = reinterpret_cast<const float4*>(x)[2 * i + 1];
            u16x8 o;
            o[0] = f2bf(v0.x); o[1] = f2bf(v0.y); o[2] = f2bf(v0.z); o[3] = f2bf(v0.w);
            o[4] = f2bf(v1.x); o[5] = f2bf(v1.y); o[6] = f2bf(v1.z); o[7] = f2bf(v1.w);
            reinterpret_cast<u16x8*>(xb)[i] = o;
        }
    }
}

// ---------------- 256x256 8-phase bf16 GEMM, 32x32x16 MFMA ----------------
// C[m][n] = sum_k A[m,k] * B[n,k].  8 waves (2M x 4N), per-wave 128x64 output
// = 4x2 grid of 32x32 tiles.  LDS per buf: A [mh][wr][64][64], B [nh][wc][32][64];
// 2 bufs = 128 KiB.  Swizzle: colbyte ^= (row&7)<<4 via pre-swizzled global
// SOURCE (linear gload_lds dest) + same XOR on ds_read (involution).

template<int MH, int NT>
__device__ __forceinline__ void mfma_quad(const bf16x8 (&a)[2][4], const bf16x8 (&b)[4],
                                          f32x16 (&acc)[4][2]) {
#pragma unroll
    for (int kc = 0; kc < 4; ++kc)
#pragma unroll
        for (int mt = 0; mt < 2; ++mt)
            acc[MH * 2 + mt][NT] = __builtin_amdgcn_mfma_f32_32x32x16_bf16(
                a[mt][kc], b[kc], acc[MH * 2 + mt][NT], 0, 0, 0);
}

__global__ __launch_bounds__(512, 2) void gemm_kernel(
    const unsigned short* __restrict__ A,   // x bf16 [8192][4096]
    const unsigned short* __restrict__ B,   // W_eff bf16 [4096][4096]
    float* __restrict__ C)                  // [8192][4096] fp32
{
    __shared__ __align__(16) char lds[131072];

    const int tid  = threadIdx.x;
    const int lane = tid & 63;
    const int wave = tid >> 6;
    const int wr = wave >> 2;          // 0..1 (M)
    const int wc = wave & 3;           // 0..3 (N)

    // bijective XCD swizzle: 512 blocks, 8 XCDs
    const int bid = blockIdx.x;
    const int swz = (bid & 7) * 64 + (bid >> 3);
    const int bm = swz >> 4;           // 0..31
    const int bn = swz & 15;           // 0..15
    const int m0 = bm * BM;
    const int n0 = bn * BN;

    // ---- staging addressing ----
    const int srccol = 8 * ((tid & 7) ^ ((tid >> 3) & 7));   // pre-swizzled col (elems)
    const int wub    = (tid & ~63) * 16;                     // wave-uniform LDS byte base
    const unsigned short* Ag = A + (size_t)(m0 + (tid >> 3)) * K_DIM + srccol;
    const unsigned short* Bg = B + (size_t)(n0 + (tid >> 8) * 64 + ((tid >> 3) & 31)) * K_DIM + srccol;

#define STAGE_A(buf, mh, kt) do { \
    __builtin_amdgcn_global_load_lds( \
        (const __attribute__((address_space(1))) void*)(Ag + (size_t)((mh) * 64) * K_DIM + (size_t)(kt) * 64), \
        (__attribute__((address_space(3))) void*)(lds + (buf) * 65536 + (mh) * 16384 + wub), 16, 0, 0); \
    __builtin_amdgcn_global_load_lds( \
        (const __attribute__((address_space(1))) void*)(Ag + (size_t)(128 + (mh) * 64) * K_DIM + (size_t)(kt) * 64), \
        (__attribute__((address_space(3))) void*)(lds + (buf) * 65536 + (mh) * 16384 + 8192 + wub), 16, 0, 0); \
} while (0)

#define STAGE_B(buf, nh, kt) do { \
    __builtin_amdgcn_global_load_lds( \
        (const __attribute__((address_space(1))) void*)(Bg + (size_t)((nh) * 32) * K_DIM + (size_t)(kt) * 64), \
        (__attribute__((address_space(3))) void*)(lds + (buf) * 65536 + 32768 + (nh) * 16384 + wub), 16, 0, 0); \
    __builtin_amdgcn_global_load_lds( \
        (const __attribute__((address_space(1))) void*)(Bg + (size_t)(128 + (nh) * 32) * K_DIM + (size_t)(kt) * 64), \
        (__attribute__((address_space(3))) void*)(lds + (buf) * 65536 + 32768 + (nh) * 16384 + 8192 + wub), 16, 0, 0); \
} while (0)

    // ---- read-side addressing (32x32x16 frags) ----
    // A frag: lane l -> row (l&31), k = (l>>5)*8 + j ;  B frag: col (l&31), same k
    const int wrA   = wr * 8192;               // wave's row-half byte base in A block
    const int wcB   = wc * 4096;               // wave's col block byte base in B block
    const int rdrow = (lane & 31) * 128;       // row byte offset (32 rows)
    const int rdxor = (lane & 7) << 4;         // swizzle XOR ((row&7)<<4)
    const int rdg   = (lane >> 5) * 16;        // 16B k-slot

#define RD_A(dst, buf, mh) do { \
    _Pragma("unroll") for (int mt = 0; mt < 2; ++mt) \
    _Pragma("unroll") for (int kc = 0; kc < 4; ++kc) \
        dst[mt][kc] = *(const bf16x8*)(lds + (buf) * 65536 + (mh) * 16384 + wrA + mt * 4096 + rdrow + ((kc * 32 + rdg) ^ rdxor)); \
} while (0)

#define RD_B(dst, buf, nh) do { \
    _Pragma("unroll") for (int kc = 0; kc < 4; ++kc) \
        dst[kc] = *(const bf16x8*)(lds + (buf) * 65536 + 32768 + (nh) * 16384 + wcB + rdrow + ((kc * 32 + rdg) ^ rdxor)); \
} while (0)

#define PH_TAIL(QUAD) \
    __builtin_amdgcn_s_barrier(); \
    asm volatile("s_waitcnt lgkmcnt(0)" ::: "memory"); \
    __builtin_amdgcn_s_setprio(1); \
    QUAD; \
    __builtin_amdgcn_s_setprio(0);

    f32x16 acc[4][2];
#pragma unroll
    for (int i = 0; i < 4; ++i)
#pragma unroll
        for (int j = 0; j < 2; ++j)
#pragma unroll
            for (int r = 0; r < 16; ++r) acc[i][j][r] = 0.f;

    bf16x8 afr[2][4];    // current mh-half A frags
    bf16x8 b0[4], b1[4]; // both B col-half frags (held across phases)

    // ---- prologue: tile0 (4 halves) + tile1 (A0,B1) ----
    STAGE_A(0, 0, 0); STAGE_B(0, 1, 0); STAGE_A(0, 1, 0); STAGE_B(0, 0, 0);
    STAGE_A(1, 0, 1); STAGE_B(1, 1, 1);
    asm volatile("s_waitcnt vmcnt(4)" ::: "memory");  // tile0 fully landed (8 ops drained)
    __builtin_amdgcn_s_barrier();

    for (int it = 0; it < NKT / 2; ++it) {
        const int k1 = 2 * it + 1;
        const int k2 = (2 * it + 2) & (NKT - 1);   // dummy re-stage on last iter (safe)
        const int k3 = (2 * it + 3) & (NKT - 1);

        // P1: buf0 quad(0,0)
        RD_A(afr, 0, 0); RD_B(b0, 0, 0);
        STAGE_A(1, 1, k1);
        PH_TAIL((mfma_quad<0, 0>(afr, b0, acc)));
        __builtin_amdgcn_s_barrier();
        // P2: buf0 quad(0,1)
        RD_B(b1, 0, 1);
        STAGE_B(1, 0, k1);
        PH_TAIL((mfma_quad<0, 1>(afr, b1, acc)));
        __builtin_amdgcn_s_barrier();
        // P3: buf0 quad(1,1)
        RD_A(afr, 0, 1);
        STAGE_A(0, 0, k2);
        PH_TAIL((mfma_quad<1, 1>(afr, b1, acc)));
        __builtin_amdgcn_s_barrier();
        // P4: buf0 quad(1,0) — no ds_reads; counted vmcnt then barrier
        STAGE_B(0, 1, k2);
        PH_TAIL((mfma_quad<1, 0>(afr, b0, acc)));
        asm volatile("s_waitcnt vmcnt(4)" ::: "memory");
        __builtin_amdgcn_s_barrier();
        // P5: buf1 quad(0,0)
        RD_A(afr, 1, 0); RD_B(b0, 1, 0);
        STAGE_A(0, 1, k2);
        PH_TAIL((mfma_quad<0, 0>(afr, b0, acc)));
        __builtin_amdgcn_s_barrier();
        // P6: buf1 quad(0,1)
        RD_B(b1, 1, 1);
        STAGE_B(0, 0, k2);
        PH_TAIL((mfma_quad<0, 1>(afr, b1, acc)));
        __builtin_amdgcn_s_barrier();
        // P7: buf1 quad(1,1)
        RD_A(afr, 1, 1);
        STAGE_A(1, 0, k3);
        PH_TAIL((mfma_quad<1, 1>(afr, b1, acc)));
        __builtin_amdgcn_s_barrier();
        // P8: buf1 quad(1,0) — no ds_reads; counted vmcnt then barrier
        STAGE_B(1, 1, k3);
        PH_TAIL((mfma_quad<1, 0>(afr, b0, acc)));
        asm volatile("s_waitcnt vmcnt(4)" ::: "memory");
        __builtin_amdgcn_s_barrier();
    }

    // ---- epilogue: 32x32 D frag: col = lane&31, row = (reg&3)+8*(reg>>2)+4*(lane>>5)
    const int crow = m0 + wr * 128 + 4 * (lane >> 5);
    const int ccol = n0 + wc * 64 + (lane & 31);
#pragma unroll
    for (int mt = 0; mt < 4; ++mt)
#pragma unroll
        for (int nt = 0; nt < 2; ++nt)
#pragma unroll
            for (int r = 0; r < 16; ++r)
                C[(size_t)(crow + mt * 32 + (r & 3) + 8 * (r >> 2)) * N_DIM + ccol + nt * 32] =
                    acc[mt][nt][r];

#undef STAGE_A
#undef STAGE_B
#undef RD_A
#undef RD_B
#undef PH_TAIL
}

extern "C" void kernel_launch(void* const* d_in, const int* in_sizes, int n_in,
                              void* d_out, int out_size, void* d_ws, size_t ws_size,
                              hipStream_t stream) {
    const float* x  = (const float*)d_in[0];
    const float* wp = (const float*)d_in[1];
    const float* lA = (const float*)d_in[2];
    const float* lB = (const float*)d_in[3];
    const int*   sc = (const int*)d_in[4];
    float* out = (float*)d_out;

    unsigned short* xb   = (unsigned short*)d_ws;                               // 64 MB
    unsigned short* weff = (unsigned short*)d_ws + (size_t)M_DIM * K_DIM;       // 32 MB

    prep_kernel<<<N_DIM + CONV_BLOCKS, 256, 0, stream>>>(x, wp, lA, lB, sc, xb, weff);

    int grid = (M_DIM / BM) * (N_DIM / BN);   // 32 * 16 = 512
    gemm_kernel<<<grid, 512, 0, stream>>>(xb, weff, out);
}

// Round 4
// 282.778 us; speedup vs baseline: 1.4260x; 1.4260x over previous
//
#include <hip/hip_runtime.h>
#include <hip/hip_bf16.h>
#include <stdint.h>

#define M_DIM 8192
#define N_DIM 4096
#define K_DIM 4096
#define RANK  16

#define BM 256
#define BN 256
#define BK 64
#define NKT (K_DIM / BK)   // 64 K-tiles

typedef __attribute__((ext_vector_type(8))) __bf16 bf16x8;
typedef __attribute__((ext_vector_type(4))) float  f32x4;
typedef __attribute__((ext_vector_type(8))) unsigned short u16x8;

__device__ __forceinline__ unsigned short f2bf(float f) {
    union { float f; uint32_t u; } c; c.f = f;
    uint32_t b = c.u;
    b += 0x7FFFu + ((b >> 16) & 1u);   // RNE (finite data)
    return (unsigned short)(b >> 16);
}

// ---------------- fused prep ----------------
// blocks [0, 1024): W_eff 32-row x 512-col tiles, lA tile staged in LDS
// blocks [1024, 1024+CONV_BLOCKS): x fp32 -> bf16 convert
#define WEFF_BLOCKS 1024   // (4096/32) * (4096/512) = 128 * 8
#define CONV_BLOCKS 2048
__global__ __launch_bounds__(256) void prep_kernel(
    const float* __restrict__ x,
    const float* __restrict__ wp,   // [4096][1024]
    const float* __restrict__ lA,   // [16][4096]
    const float* __restrict__ lB,   // [4096][16]
    const int*   __restrict__ scaling,
    unsigned short* __restrict__ xb,     // [8192][4096] bf16
    unsigned short* __restrict__ weff) { // [4096][4096] bf16
    __shared__ float lAs[16][512];       // 32 KiB
    const int t = threadIdx.x;
    if (blockIdx.x < WEFF_BLOCKS) {
        const int bo = blockIdx.x >> 3;        // 0..127 (row tile of 32)
        const int bi = blockIdx.x & 7;         // 0..7   (col tile of 512)
        // stage lA[16][bi*512 .. +512) : 2048 float4, 8 per thread
#pragma unroll
        for (int v = 0; v < 8; ++v) {
            int idx = v * 256 + t;             // float4 index, 128 per row
            int r = idx >> 7;
            int c4 = idx & 127;
            reinterpret_cast<float4*>(&lAs[r][0])[c4] =
                reinterpret_cast<const float4*>(lA + (size_t)r * 4096 + bi * 512)[c4];
        }
        __syncthreads();
        const int row = t >> 3;                // 0..31
        const int o = bo * 32 + row;
        const float s = (float)scaling[0];
        float b[RANK];
#pragma unroll
        for (int r = 0; r < RANK; ++r) b[r] = lB[o * RANK + r] * s;
        const float* wrow = wp + (size_t)o * 1024;
        const int cbase = (t & 7) * 4;         // col-interleaved: conflict-free LDS reads
#pragma unroll
        for (int j = 0; j < 16; ++j) {
            int c = cbase + j * 32;            // col within 512 tile
            int gi = bi * 512 + c;             // global i
            float4 w = *reinterpret_cast<const float4*>(wrow + (gi & 1023));
            float a0 = w.x, a1 = w.y, a2 = w.z, a3 = w.w;
#pragma unroll
            for (int r = 0; r < RANK; ++r) {
                float4 la = *reinterpret_cast<const float4*>(&lAs[r][c]);
                a0 = fmaf(b[r], la.x, a0);
                a1 = fmaf(b[r], la.y, a1);
                a2 = fmaf(b[r], la.z, a2);
                a3 = fmaf(b[r], la.w, a3);
            }
            ushort4 ov;
            ov.x = f2bf(a0); ov.y = f2bf(a1); ov.z = f2bf(a2); ov.w = f2bf(a3);
            *reinterpret_cast<ushort4*>(weff + (size_t)o * 4096 + gi) = ov;
        }
    } else {
        const int n8 = (M_DIM * K_DIM) / 8;
        int idx = (blockIdx.x - WEFF_BLOCKS) * 256 + t;
        const int stride = CONV_BLOCKS * 256;
        for (int i = idx; i < n8; i += stride) {
            float4 v0 = reinterpret_cast<const float4*>(x)[2 * i];
            float4 v1 = reinterpret_cast<const float4*>(x)[2 * i + 1];
            u16x8 o;
            o[0] = f2bf(v0.x); o[1] = f2bf(v0.y); o[2] = f2bf(v0.z); o[3] = f2bf(v0.w);
            o[4] = f2bf(v1.x); o[5] = f2bf(v1.y); o[6] = f2bf(v1.z); o[7] = f2bf(v1.w);
            reinterpret_cast<u16x8*>(xb)[i] = o;
        }
    }
}

// ---------------- 256x256 8-phase bf16 GEMM (Round-2 verified structure) ----------------
// C[m][n] = sum_k A[m,k] * B[n,k].  8 waves (2M x 4N), per-wave 128x64 output.
// LDS per buf: A [mh][wr][64][64], B [nh][wc][32][64]; 2 bufs = 128 KiB.
// Swizzle: colbyte ^= (row&7)<<4 via pre-swizzled global SOURCE (linear
// gload_lds dest) + same XOR on ds_read (involution).  16x16x32 MFMA.

template<int MH, int NH>
__device__ __forceinline__ void mfma_quad(const bf16x8 (&a)[4][2], const bf16x8 (&b)[2][2],
                                          f32x4 (&acc)[8][4]) {
#pragma unroll
    for (int kc = 0; kc < 2; ++kc)
#pragma unroll
        for (int mf = 0; mf < 4; ++mf)
#pragma unroll
            for (int nf = 0; nf < 2; ++nf)
                acc[MH * 4 + mf][NH * 2 + nf] = __builtin_amdgcn_mfma_f32_16x16x32_bf16(
                    a[mf][kc], b[nf][kc], acc[MH * 4 + mf][NH * 2 + nf], 0, 0, 0);
}

__global__ __launch_bounds__(512, 2) void gemm_kernel(
    const unsigned short* __restrict__ A,   // x bf16 [8192][4096]
    const unsigned short* __restrict__ B,   // W_eff bf16 [4096][4096]
    float* __restrict__ C)                  // [8192][4096] fp32
{
    __shared__ __align__(16) char lds[131072];

    const int tid  = threadIdx.x;
    const int lane = tid & 63;
    const int wave = tid >> 6;
    const int wr = wave >> 2;          // 0..1 (M)
    const int wc = wave & 3;           // 0..3 (N)

    // bijective XCD swizzle: 512 blocks, 8 XCDs
    const int bid = blockIdx.x;
    const int swz = (bid & 7) * 64 + (bid >> 3);
    const int bm = swz >> 4;           // 0..31
    const int bn = swz & 15;           // 0..15
    const int m0 = bm * BM;
    const int n0 = bn * BN;

    // ---- staging addressing ----
    const int srccol = 8 * ((tid & 7) ^ ((tid >> 3) & 7));   // pre-swizzled col (elems)
    const int wub    = (tid & ~63) * 16;                     // wave-uniform LDS byte base
    const unsigned short* Ag = A + (size_t)(m0 + (tid >> 3)) * K_DIM + srccol;
    const unsigned short* Bg = B + (size_t)(n0 + (tid >> 8) * 64 + ((tid >> 3) & 31)) * K_DIM + srccol;

#define STAGE_A(buf, mh, kt) do { \
    __builtin_amdgcn_global_load_lds( \
        (const __attribute__((address_space(1))) void*)(Ag + (size_t)((mh) * 64) * K_DIM + (size_t)(kt) * 64), \
        (__attribute__((address_space(3))) void*)(lds + (buf) * 65536 + (mh) * 16384 + wub), 16, 0, 0); \
    __builtin_amdgcn_global_load_lds( \
        (const __attribute__((address_space(1))) void*)(Ag + (size_t)(128 + (mh) * 64) * K_DIM + (size_t)(kt) * 64), \
        (__attribute__((address_space(3))) void*)(lds + (buf) * 65536 + (mh) * 16384 + 8192 + wub), 16, 0, 0); \
} while (0)

#define STAGE_B(buf, nh, kt) do { \
    __builtin_amdgcn_global_load_lds( \
        (const __attribute__((address_space(1))) void*)(Bg + (size_t)((nh) * 32) * K_DIM + (size_t)(kt) * 64), \
        (__attribute__((address_space(3))) void*)(lds + (buf) * 65536 + 32768 + (nh) * 16384 + wub), 16, 0, 0); \
    __builtin_amdgcn_global_load_lds( \
        (const __attribute__((address_space(1))) void*)(Bg + (size_t)(128 + (nh) * 32) * K_DIM + (size_t)(kt) * 64), \
        (__attribute__((address_space(3))) void*)(lds + (buf) * 65536 + 32768 + (nh) * 16384 + 8192 + wub), 16, 0, 0); \
} while (0)

    // ---- read-side addressing (16x16x32 frags) ----
    const int wrA   = wr * 8192;
    const int wcB   = wc * 4096;
    const int rdrow = (lane & 15) * 128;           // row byte offset
    const int rdxor = (lane & 7) << 4;             // swizzle XOR (row&7)<<4
    const int rdg   = (lane >> 4) * 16;            // 16B slot

#define RD_A(dst, buf, mh) do { \
    _Pragma("unroll") for (int mf = 0; mf < 4; ++mf) \
    _Pragma("unroll") for (int kc = 0; kc < 2; ++kc) \
        dst[mf][kc] = *(const bf16x8*)(lds + (buf) * 65536 + (mh) * 16384 + wrA + rdrow + mf * 2048 + ((kc * 64 + rdg) ^ rdxor)); \
} while (0)

#define RD_B(dst, buf, nh) do { \
    _Pragma("unroll") for (int nf = 0; nf < 2; ++nf) \
    _Pragma("unroll") for (int kc = 0; kc < 2; ++kc) \
        dst[nf][kc] = *(const bf16x8*)(lds + (buf) * 65536 + 32768 + (nh) * 16384 + wcB + rdrow + nf * 2048 + ((kc * 64 + rdg) ^ rdxor)); \
} while (0)

#define PH_TAIL(QUAD) \
    __builtin_amdgcn_s_barrier(); \
    asm volatile("s_waitcnt lgkmcnt(0)" ::: "memory"); \
    __builtin_amdgcn_s_setprio(1); \
    QUAD; \
    __builtin_amdgcn_s_setprio(0);

    f32x4 acc[8][4];
#pragma unroll
    for (int i = 0; i < 8; ++i)
#pragma unroll
        for (int j = 0; j < 4; ++j) acc[i][j] = (f32x4){0.f, 0.f, 0.f, 0.f};

    bf16x8 afr[4][2];
    bf16x8 bfr[2][2];

    // ---- prologue: tile0 (4 halves) + tile1 (A0,B1) ----
    STAGE_A(0, 0, 0); STAGE_B(0, 1, 0); STAGE_A(0, 1, 0); STAGE_B(0, 0, 0);
    STAGE_A(1, 0, 1); STAGE_B(1, 1, 1);
    asm volatile("s_waitcnt vmcnt(4)" ::: "memory");
    __builtin_amdgcn_s_barrier();

    for (int it = 0; it < NKT / 2; ++it) {
        const int k1 = 2 * it + 1;
        const int k2 = (2 * it + 2) & (NKT - 1);   // dummy re-stage on last iter (safe)
        const int k3 = (2 * it + 3) & (NKT - 1);

        // P1: buf0 quad(0,0)  [12 ds_reads -> partial lgkm wait pre-barrier]
        RD_A(afr, 0, 0); RD_B(bfr, 0, 0);
        STAGE_A(1, 1, k1);
        asm volatile("s_waitcnt lgkmcnt(8)" ::: "memory");
        PH_TAIL((mfma_quad<0, 0>(afr, bfr, acc)));
        __builtin_amdgcn_s_barrier();
        // P2: buf0 quad(0,1)
        RD_B(bfr, 0, 1);
        STAGE_B(1, 0, k1);
        PH_TAIL((mfma_quad<0, 1>(afr, bfr, acc)));
        __builtin_amdgcn_s_barrier();
        // P3: buf0 quad(1,1)
        RD_A(afr, 0, 1);
        STAGE_A(0, 0, k2);
        PH_TAIL((mfma_quad<1, 1>(afr, bfr, acc)));
        __builtin_amdgcn_s_barrier();
        // P4: buf0 quad(1,0) + counted vmcnt (buf1 tile k1 complete after barrier)
        RD_B(bfr, 0, 0);
        STAGE_B(0, 1, k2);
        PH_TAIL((mfma_quad<1, 0>(afr, bfr, acc)));
        asm volatile("s_waitcnt vmcnt(4)" ::: "memory");
        __builtin_amdgcn_s_barrier();
        // P5: buf1 quad(0,0)
        RD_A(afr, 1, 0); RD_B(bfr, 1, 0);
        STAGE_A(0, 1, k2);
        asm volatile("s_waitcnt lgkmcnt(8)" ::: "memory");
        PH_TAIL((mfma_quad<0, 0>(afr, bfr, acc)));
        __builtin_amdgcn_s_barrier();
        // P6: buf1 quad(0,1)
        RD_B(bfr, 1, 1);
        STAGE_B(0, 0, k2);
        PH_TAIL((mfma_quad<0, 1>(afr, bfr, acc)));
        __builtin_amdgcn_s_barrier();
        // P7: buf1 quad(1,1)
        RD_A(afr, 1, 1);
        STAGE_A(1, 0, k3);
        PH_TAIL((mfma_quad<1, 1>(afr, bfr, acc)));
        __builtin_amdgcn_s_barrier();
        // P8: buf1 quad(1,0) + counted vmcnt (buf0 tile k2 complete after barrier)
        RD_B(bfr, 1, 0);
        STAGE_B(1, 1, k3);
        PH_TAIL((mfma_quad<1, 0>(afr, bfr, acc)));
        asm volatile("s_waitcnt vmcnt(4)" ::: "memory");
        __builtin_amdgcn_s_barrier();
    }

    // ---- epilogue: D frag: col = lane&15, row = (lane>>4)*4 + r ----
    const int crow = m0 + wr * 128 + (lane >> 4) * 4;
    const int ccol = n0 + wc * 64 + (lane & 15);
#pragma unroll
    for (int mi = 0; mi < 8; ++mi)
#pragma unroll
        for (int ni = 0; ni < 4; ++ni)
#pragma unroll
            for (int r = 0; r < 4; ++r)
                C[(size_t)(crow + mi * 16 + r) * N_DIM + ccol + ni * 16] = acc[mi][ni][r];

#undef STAGE_A
#undef STAGE_B
#undef RD_A
#undef RD_B
#undef PH_TAIL
}

extern "C" void kernel_launch(void* const* d_in, const int* in_sizes, int n_in,
                              void* d_out, int out_size, void* d_ws, size_t ws_size,
                              hipStream_t stream) {
    const float* x  = (const float*)d_in[0];
    const float* wp = (const float*)d_in[1];
    const float* lA = (const float*)d_in[2];
    const float* lB = (const float*)d_in[3];
    const int*   sc = (const int*)d_in[4];
    float* out = (float*)d_out;

    unsigned short* xb   = (unsigned short*)d_ws;                               // 64 MB
    unsigned short* weff = (unsigned short*)d_ws + (size_t)M_DIM * K_DIM;       // 32 MB

    prep_kernel<<<WEFF_BLOCKS + CONV_BLOCKS, 256, 0, stream>>>(x, wp, lA, lB, sc, xb, weff);

    int grid = (M_DIM / BM) * (N_DIM / BN);   // 32 * 16 = 512
    gemm_kernel<<<grid, 512, 0, stream>>>(xb, weff, out);
}

// Round 5
// 271.195 us; speedup vs baseline: 1.4869x; 1.0427x over previous
//
#include <hip/hip_runtime.h>
#include <hip/hip_bf16.h>
#include <stdint.h>

#define M_DIM 8192
#define N_DIM 4096
#define K_DIM 4096
#define RANK  16

#define BM 256
#define BN 256
#define BK 64
#define NKT (K_DIM / BK)   // 64 K-tiles

typedef __attribute__((ext_vector_type(8))) __bf16 bf16x8;
typedef __attribute__((ext_vector_type(4))) float  f32x4;
typedef __attribute__((ext_vector_type(8))) unsigned short u16x8;

__device__ __forceinline__ unsigned short f2bf(float f) {
    union { float f; uint32_t u; } c; c.f = f;
    uint32_t b = c.u;
    b += 0x7FFFu + ((b >> 16) & 1u);   // RNE (finite data)
    return (unsigned short)(b >> 16);
}

// ---------------- fused prep ----------------
// blocks [0, 1024): W_eff 32-row x 512-col tiles, lA tile staged in LDS
// blocks [1024, 1024+CONV_BLOCKS): x fp32 -> bf16 convert
#define WEFF_BLOCKS 1024   // (4096/32) * (4096/512)
#define CONV_BLOCKS 2048
__global__ __launch_bounds__(256) void prep_kernel(
    const float* __restrict__ x,
    const float* __restrict__ wp,   // [4096][1024]
    const float* __restrict__ lA,   // [16][4096]
    const float* __restrict__ lB,   // [4096][16]
    const int*   __restrict__ scaling,
    unsigned short* __restrict__ xb,     // [8192][4096] bf16
    unsigned short* __restrict__ weff) { // [4096][4096] bf16
    __shared__ float lAs[16][512];       // 32 KiB
    const int t = threadIdx.x;
    if (blockIdx.x < WEFF_BLOCKS) {
        const int bo = blockIdx.x >> 3;        // 0..127 (row tile of 32)
        const int bi = blockIdx.x & 7;         // 0..7   (col tile of 512)
#pragma unroll
        for (int v = 0; v < 8; ++v) {
            int idx = v * 256 + t;             // float4 index, 128 per row
            int r = idx >> 7;
            int c4 = idx & 127;
            reinterpret_cast<float4*>(&lAs[r][0])[c4] =
                reinterpret_cast<const float4*>(lA + (size_t)r * 4096 + bi * 512)[c4];
        }
        __syncthreads();
        const int row = t >> 3;                // 0..31
        const int o = bo * 32 + row;
        const float s = (float)scaling[0];
        float b[RANK];
#pragma unroll
        for (int r = 0; r < RANK; ++r) b[r] = lB[o * RANK + r] * s;
        const float* wrow = wp + (size_t)o * 1024;
        const int cbase = (t & 7) * 4;         // col-interleaved: conflict-free LDS reads
#pragma unroll
        for (int j = 0; j < 16; ++j) {
            int c = cbase + j * 32;
            int gi = bi * 512 + c;
            float4 w = *reinterpret_cast<const float4*>(wrow + (gi & 1023));
            float a0 = w.x, a1 = w.y, a2 = w.z, a3 = w.w;
#pragma unroll
            for (int r = 0; r < RANK; ++r) {
                float4 la = *reinterpret_cast<const float4*>(&lAs[r][c]);
                a0 = fmaf(b[r], la.x, a0);
                a1 = fmaf(b[r], la.y, a1);
                a2 = fmaf(b[r], la.z, a2);
                a3 = fmaf(b[r], la.w, a3);
            }
            ushort4 ov;
            ov.x = f2bf(a0); ov.y = f2bf(a1); ov.z = f2bf(a2); ov.w = f2bf(a3);
            *reinterpret_cast<ushort4*>(weff + (size_t)o * 4096 + gi) = ov;
        }
    } else {
        const int n8 = (M_DIM * K_DIM) / 8;
        int idx = (blockIdx.x - WEFF_BLOCKS) * 256 + t;
        const int stride = CONV_BLOCKS * 256;
        for (int i = idx; i < n8; i += stride) {
            float4 v0 = reinterpret_cast<const float4*>(x)[2 * i];
            float4 v1 = reinterpret_cast<const float4*>(x)[2 * i + 1];
            u16x8 o;
            o[0] = f2bf(v0.x); o[1] = f2bf(v0.y); o[2] = f2bf(v0.z); o[3] = f2bf(v0.w);
            o[4] = f2bf(v1.x); o[5] = f2bf(v1.y); o[6] = f2bf(v1.z); o[7] = f2bf(v1.w);
            reinterpret_cast<u16x8*>(xb)[i] = o;
        }
    }
}

// ---------------- 256x256 8-phase bf16 GEMM ----------------
// vs Round-4: (1) trailing barrier removed at non-vmcnt phases (hazard table
// re-verified: every stage target last read >= 2 phases before issue),
// (2) B frags held in registers across phases (P4/P8 read-free),
// (3) LDS-repack epilogue for full-line coalesced C stores.

template<int MH, int NH>
__device__ __forceinline__ void mfma_quad(const bf16x8 (&a)[4][2], const bf16x8 (&b)[2][2],
                                          f32x4 (&acc)[8][4]) {
#pragma unroll
    for (int kc = 0; kc < 2; ++kc)
#pragma unroll
        for (int mf = 0; mf < 4; ++mf)
#pragma unroll
            for (int nf = 0; nf < 2; ++nf)
                acc[MH * 4 + mf][NH * 2 + nf] = __builtin_amdgcn_mfma_f32_16x16x32_bf16(
                    a[mf][kc], b[nf][kc], acc[MH * 4 + mf][NH * 2 + nf], 0, 0, 0);
}

__global__ __launch_bounds__(512, 1) void gemm_kernel(
    const unsigned short* __restrict__ A,   // x bf16 [8192][4096]
    const unsigned short* __restrict__ B,   // W_eff bf16 [4096][4096]
    float* __restrict__ C)                  // [8192][4096] fp32
{
    __shared__ __align__(16) char lds[131072];

    const int tid  = threadIdx.x;
    const int lane = tid & 63;
    const int wave = tid >> 6;
    const int wr = wave >> 2;          // 0..1 (M)
    const int wc = wave & 3;           // 0..3 (N)

    // bijective XCD swizzle: 512 blocks, 8 XCDs
    const int bid = blockIdx.x;
    const int swz = (bid & 7) * 64 + (bid >> 3);
    const int bm = swz >> 4;           // 0..31
    const int bn = swz & 15;           // 0..15
    const int m0 = bm * BM;
    const int n0 = bn * BN;

    // ---- staging addressing ----
    const int srccol = 8 * ((tid & 7) ^ ((tid >> 3) & 7));   // pre-swizzled col (elems)
    const int wub    = (tid & ~63) * 16;                     // wave-uniform LDS byte base
    const unsigned short* Ag = A + (size_t)(m0 + (tid >> 3)) * K_DIM + srccol;
    const unsigned short* Bg = B + (size_t)(n0 + (tid >> 8) * 64 + ((tid >> 3) & 31)) * K_DIM + srccol;

#define STAGE_A(buf, mh, kt) do { \
    __builtin_amdgcn_global_load_lds( \
        (const __attribute__((address_space(1))) void*)(Ag + (size_t)((mh) * 64) * K_DIM + (size_t)(kt) * 64), \
        (__attribute__((address_space(3))) void*)(lds + (buf) * 65536 + (mh) * 16384 + wub), 16, 0, 0); \
    __builtin_amdgcn_global_load_lds( \
        (const __attribute__((address_space(1))) void*)(Ag + (size_t)(128 + (mh) * 64) * K_DIM + (size_t)(kt) * 64), \
        (__attribute__((address_space(3))) void*)(lds + (buf) * 65536 + (mh) * 16384 + 8192 + wub), 16, 0, 0); \
} while (0)

#define STAGE_B(buf, nh, kt) do { \
    __builtin_amdgcn_global_load_lds( \
        (const __attribute__((address_space(1))) void*)(Bg + (size_t)((nh) * 32) * K_DIM + (size_t)(kt) * 64), \
        (__attribute__((address_space(3))) void*)(lds + (buf) * 65536 + 32768 + (nh) * 16384 + wub), 16, 0, 0); \
    __builtin_amdgcn_global_load_lds( \
        (const __attribute__((address_space(1))) void*)(Bg + (size_t)(128 + (nh) * 32) * K_DIM + (size_t)(kt) * 64), \
        (__attribute__((address_space(3))) void*)(lds + (buf) * 65536 + 32768 + (nh) * 16384 + 8192 + wub), 16, 0, 0); \
} while (0)

    // ---- read-side addressing (16x16x32 frags) ----
    const int wrA   = wr * 8192;
    const int wcB   = wc * 4096;
    const int rdrow = (lane & 15) * 128;           // row byte offset
    const int rdxor = (lane & 7) << 4;             // swizzle XOR (row&7)<<4
    const int rdg   = (lane >> 4) * 16;            // 16B slot

#define RD_A(dst, buf, mh) do { \
    _Pragma("unroll") for (int mf = 0; mf < 4; ++mf) \
    _Pragma("unroll") for (int kc = 0; kc < 2; ++kc) \
        dst[mf][kc] = *(const bf16x8*)(lds + (buf) * 65536 + (mh) * 16384 + wrA + rdrow + mf * 2048 + ((kc * 64 + rdg) ^ rdxor)); \
} while (0)

#define RD_B(dst, buf, nh) do { \
    _Pragma("unroll") for (int nf = 0; nf < 2; ++nf) \
    _Pragma("unroll") for (int kc = 0; kc < 2; ++kc) \
        dst[nf][kc] = *(const bf16x8*)(lds + (buf) * 65536 + 32768 + (nh) * 16384 + wcB + rdrow + nf * 2048 + ((kc * 64 + rdg) ^ rdxor)); \
} while (0)

#define PH_TAIL(QUAD) \
    __builtin_amdgcn_s_barrier(); \
    asm volatile("s_waitcnt lgkmcnt(0)" ::: "memory"); \
    __builtin_amdgcn_s_setprio(1); \
    QUAD; \
    __builtin_amdgcn_s_setprio(0);

    f32x4 acc[8][4];
#pragma unroll
    for (int i = 0; i < 8; ++i)
#pragma unroll
        for (int j = 0; j < 4; ++j) acc[i][j] = (f32x4){0.f, 0.f, 0.f, 0.f};

    bf16x8 afr[4][2];
    bf16x8 b0[2][2], b1[2][2];   // register-held B frags (live across phases)

    // ---- prologue: tile0 (4 halves) + tile1 (A0,B1) ----
    STAGE_A(0, 0, 0); STAGE_B(0, 1, 0); STAGE_A(0, 1, 0); STAGE_B(0, 0, 0);
    STAGE_A(1, 0, 1); STAGE_B(1, 1, 1);
    asm volatile("s_waitcnt vmcnt(4)" ::: "memory");
    __builtin_amdgcn_s_barrier();

    for (int it = 0; it < NKT / 2; ++it) {
        const int k1 = 2 * it + 1;
        const int k2 = (2 * it + 2) & (NKT - 1);   // dummy re-stage on last iter (safe)
        const int k3 = (2 * it + 3) & (NKT - 1);

        // P1: buf0 quad(0,0)
        RD_A(afr, 0, 0); RD_B(b0, 0, 0);
        STAGE_A(1, 1, k1);
        asm volatile("s_waitcnt lgkmcnt(8)" ::: "memory");
        PH_TAIL((mfma_quad<0, 0>(afr, b0, acc)));
        // P2: buf0 quad(0,1)
        RD_B(b1, 0, 1);
        STAGE_B(1, 0, k1);
        PH_TAIL((mfma_quad<0, 1>(afr, b1, acc)));
        // P3: buf0 quad(1,1)
        RD_A(afr, 0, 1);
        STAGE_A(0, 0, k2);
        PH_TAIL((mfma_quad<1, 1>(afr, b1, acc)));
        // P4: buf0 quad(1,0) — read-free; counted vmcnt + barrier (buf1-k1 landed)
        STAGE_B(0, 1, k2);
        PH_TAIL((mfma_quad<1, 0>(afr, b0, acc)));
        asm volatile("s_waitcnt vmcnt(4)" ::: "memory");
        __builtin_amdgcn_s_barrier();
        // P5: buf1 quad(0,0)
        RD_A(afr, 1, 0); RD_B(b0, 1, 0);
        STAGE_A(0, 1, k2);
        asm volatile("s_waitcnt lgkmcnt(8)" ::: "memory");
        PH_TAIL((mfma_quad<0, 0>(afr, b0, acc)));
        // P6: buf1 quad(0,1)
        RD_B(b1, 1, 1);
        STAGE_B(0, 0, k2);
        PH_TAIL((mfma_quad<0, 1>(afr, b1, acc)));
        // P7: buf1 quad(1,1)
        RD_A(afr, 1, 1);
        STAGE_A(1, 0, k3);
        PH_TAIL((mfma_quad<1, 1>(afr, b1, acc)));
        // P8: buf1 quad(1,0) — read-free; counted vmcnt + barrier (buf0-k2 landed)
        STAGE_B(1, 1, k3);
        PH_TAIL((mfma_quad<1, 0>(afr, b0, acc)));
        asm volatile("s_waitcnt vmcnt(4)" ::: "memory");
        __builtin_amdgcn_s_barrier();
    }

    // ---- epilogue: LDS repack for full-line C stores ----
    // D frag: col = lane&15, row = (lane>>4)*4 + r.  Wave-private region
    // [16][84] f32 (stride 84 keeps banks <= 2-way on both sides).
    // Last iter leaves only buf1 stages (>= 64 KiB) in flight; region < 43 KiB.
    {
        float* lsc = (float*)lds + wave * (16 * 84);
        const int wcol  = lane & 15;
        const int wrow4 = (lane >> 4) * 4;
        const int rrow  = lane >> 3;            // 0..7
        const int rcol  = (lane & 7) * 4;       // f32 col base
        const int crow0 = m0 + wr * 128;
        const int ccol0 = n0 + wc * 64;
#pragma unroll
        for (int mi = 0; mi < 8; ++mi) {
#pragma unroll
            for (int ni = 0; ni < 4; ++ni)
#pragma unroll
                for (int r = 0; r < 4; ++r)
                    lsc[(wrow4 + r) * 84 + ni * 16 + wcol] = acc[mi][ni][r];
            asm volatile("s_waitcnt lgkmcnt(0)" ::: "memory");
#pragma unroll
            for (int rh = 0; rh < 2; ++rh)
#pragma unroll
                for (int j = 0; j < 2; ++j) {
                    f32x4 v = *(const f32x4*)&lsc[(rh * 8 + rrow) * 84 + rcol + j * 32];
                    *(f32x4*)&C[(size_t)(crow0 + mi * 16 + rh * 8 + rrow) * N_DIM +
                                ccol0 + rcol + j * 32] = v;
                }
            asm volatile("s_waitcnt lgkmcnt(0)" ::: "memory");
        }
    }

#undef STAGE_A
#undef STAGE_B
#undef RD_A
#undef RD_B
#undef PH_TAIL
}

extern "C" void kernel_launch(void* const* d_in, const int* in_sizes, int n_in,
                              void* d_out, int out_size, void* d_ws, size_t ws_size,
                              hipStream_t stream) {
    const float* x  = (const float*)d_in[0];
    const float* wp = (const float*)d_in[1];
    const float* lA = (const float*)d_in[2];
    const float* lB = (const float*)d_in[3];
    const int*   sc = (const int*)d_in[4];
    float* out = (float*)d_out;

    unsigned short* xb   = (unsigned short*)d_ws;                               // 64 MB
    unsigned short* weff = (unsigned short*)d_ws + (size_t)M_DIM * K_DIM;       // 32 MB

    prep_kernel<<<WEFF_BLOCKS + CONV_BLOCKS, 256, 0, stream>>>(x, wp, lA, lB, sc, xb, weff);

    int grid = (M_DIM / BM) * (N_DIM / BN);   // 32 * 16 = 512
    gemm_kernel<<<grid, 512, 0, stream>>>(xb, weff, out);
}